// Round 1
// baseline (16163.428 us; speedup 1.0000x reference)
//
#include <hip/hip_runtime.h>

// LightGCN: e_{k+1} = A @ e_k (scatter-add SpMM), acc = sum e_k, out = dot of gathered rows / 16.
// N = 150000, d = 64, nnz = 6.4M, 3 layers, 4096 queries.

constexpr int D = 64;

// ---- concat copy: e0 = [user_emb; item_emb], vectorized float4 ----
__global__ __launch_bounds__(256) void concat_copy(const float4* __restrict__ u4,
                                                   const float4* __restrict__ i4,
                                                   float4* __restrict__ e4,
                                                   long long nU4, long long total4) {
    long long t = (long long)blockIdx.x * blockDim.x + threadIdx.x;
    if (t >= total4) return;
    e4[t] = (t < nU4) ? u4[t] : i4[t - nU4];
}

// ---- init query accumulators with layer-0 embeddings ----
__global__ __launch_bounds__(64) void gather_init(const float* __restrict__ ue,
                                                  const float* __restrict__ ie,
                                                  const int* __restrict__ uidx,
                                                  const int* __restrict__ iidx,
                                                  float* __restrict__ accU,
                                                  float* __restrict__ accI) {
    int j = blockIdx.x;
    int lane = threadIdx.x;  // 64 lanes = 64 dims
    accU[(size_t)j * D + lane] = ue[(size_t)uidx[j] * D + lane];
    accI[(size_t)j * D + lane] = ie[(size_t)iidx[j] * D + lane];
}

// ---- SpMM scatter-add: 16 threads per edge, float4 per thread ----
__global__ __launch_bounds__(256) void spmm_atomic(const float* __restrict__ adj,
                                                   const int* __restrict__ idx,
                                                   const float* __restrict__ e_cur,
                                                   float* __restrict__ e_next,
                                                   long long nnz) {
    long long t = (long long)blockIdx.x * blockDim.x + threadIdx.x;
    long long edge = t >> 4;
    int sub = (int)(t & 15);
    if (edge >= nnz) return;
    int row = idx[2 * edge];
    int col = idx[2 * edge + 1];
    float w = adj[edge];
    const float4* src = (const float4*)(e_cur + (size_t)col * D);
    float4 v = src[sub];
    float* dst = e_next + (size_t)row * D + sub * 4;
    atomicAdd(dst + 0, w * v.x);
    atomicAdd(dst + 1, w * v.y);
    atomicAdd(dst + 2, w * v.z);
    atomicAdd(dst + 3, w * v.w);
}

// ---- fold one layer's gathered rows into the query accumulators ----
__global__ __launch_bounds__(64) void gather_acc(const float* __restrict__ e,
                                                 const int* __restrict__ uidx,
                                                 const int* __restrict__ iidx,
                                                 float* __restrict__ accU,
                                                 float* __restrict__ accI,
                                                 int n_users) {
    int j = blockIdx.x;
    int lane = threadIdx.x;
    accU[(size_t)j * D + lane] += e[(size_t)uidx[j] * D + lane];
    accI[(size_t)j * D + lane] += e[((size_t)n_users + iidx[j]) * D + lane];
}

// ---- final dot: out[j] = dot(accU[j], accI[j]) / 16 ----
__global__ __launch_bounds__(64) void final_dot(const float* __restrict__ accU,
                                                const float* __restrict__ accI,
                                                float* __restrict__ out) {
    int j = blockIdx.x;
    int lane = threadIdx.x;
    float p = accU[(size_t)j * D + lane] * accI[(size_t)j * D + lane];
    #pragma unroll
    for (int off = 32; off > 0; off >>= 1) p += __shfl_down(p, off);
    if (lane == 0) out[j] = p * (1.0f / 16.0f);  // (acc/4)·(acc/4)
}

extern "C" void kernel_launch(void* const* d_in, const int* in_sizes, int n_in,
                              void* d_out, int out_size, void* d_ws, size_t ws_size,
                              hipStream_t stream) {
    const float* user_emb = (const float*)d_in[0];
    const float* item_emb = (const float*)d_in[1];
    const float* adj_data = (const float*)d_in[2];
    const int* adj_indices = (const int*)d_in[3];
    const int* user_idx = (const int*)d_in[4];
    const int* item_idx = (const int*)d_in[5];
    float* out = (float*)d_out;

    const int n_users = in_sizes[0] / D;
    const int n_items = in_sizes[1] / D;
    const long long nnz = in_sizes[2];
    const int N = n_users + n_items;
    const int nq = in_sizes[4];  // 4096

    // workspace layout
    float* e0 = (float*)d_ws;
    float* e1 = e0 + (size_t)N * D;
    float* accU = e1 + (size_t)N * D;
    float* accI = accU + (size_t)nq * D;

    const size_t e_bytes = (size_t)N * D * sizeof(float);

    // e0 = concat(user_emb, item_emb)
    {
        long long total4 = (long long)N * (D / 4);
        long long nU4 = (long long)n_users * (D / 4);
        int blocks = (int)((total4 + 255) / 256);
        concat_copy<<<blocks, 256, 0, stream>>>((const float4*)user_emb,
                                                (const float4*)item_emb,
                                                (float4*)e0, nU4, total4);
    }
    // accU/accI = layer-0 gathered embeddings
    gather_init<<<nq, 64, 0, stream>>>(user_emb, item_emb, user_idx, item_idx, accU, accI);

    const long long spmm_threads = nnz * 16;
    const int spmm_blocks = (int)((spmm_threads + 255) / 256);

    float* cur = e0;
    float* nxt = e1;
    for (int layer = 0; layer < 3; ++layer) {
        hipMemsetAsync(nxt, 0, e_bytes, stream);
        spmm_atomic<<<spmm_blocks, 256, 0, stream>>>(adj_data, adj_indices, cur, nxt, nnz);
        gather_acc<<<nq, 64, 0, stream>>>(nxt, user_idx, item_idx, accU, accI, n_users);
        float* tmp = cur; cur = nxt; nxt = tmp;
    }

    final_dot<<<nq, 64, 0, stream>>>(accU, accI, out);
}

// Round 2
// 1314.627 us; speedup vs baseline: 12.2951x; 12.2951x over previous
//
#include <hip/hip_runtime.h>

// LightGCN on MI355X.
// N = 150000 nodes, d = 64, nnz = 6.4M edges, 3 layers, 4096 queries.
// Strategy: build CSR once per launch (edges identical across layers), then each
// SpMM is a per-row gather with register accumulation — zero f32 atomics.

constexpr int D = 64;

// ---- concat copy: e0 = [user_emb; item_emb] ----
__global__ __launch_bounds__(256) void concat_copy(const float4* __restrict__ u4,
                                                   const float4* __restrict__ i4,
                                                   float4* __restrict__ e4,
                                                   long long nU4, long long total4) {
    long long t = (long long)blockIdx.x * blockDim.x + threadIdx.x;
    if (t >= total4) return;
    e4[t] = (t < nU4) ? u4[t] : i4[t - nU4];
}

// ---- init query accumulators with layer-0 embeddings ----
__global__ __launch_bounds__(64) void gather_init(const float* __restrict__ ue,
                                                  const float* __restrict__ ie,
                                                  const int* __restrict__ uidx,
                                                  const int* __restrict__ iidx,
                                                  float* __restrict__ accU,
                                                  float* __restrict__ accI) {
    int j = blockIdx.x;
    int lane = threadIdx.x;
    accU[(size_t)j * D + lane] = ue[(size_t)uidx[j] * D + lane];
    accI[(size_t)j * D + lane] = ie[(size_t)iidx[j] * D + lane];
}

// ---- CSR build step 1: histogram of row ids (int atomics, cheap) ----
__global__ __launch_bounds__(256) void edge_hist(const int2* __restrict__ idx2,
                                                 int* __restrict__ counts,
                                                 long long nnz) {
    long long e = (long long)blockIdx.x * blockDim.x + threadIdx.x;
    if (e >= nnz) return;
    atomicAdd(&counts[idx2[e].x], 1);
}

// ---- CSR build step 2a: per-block exclusive scan (1024 elems/block) ----
__global__ __launch_bounds__(1024) void scan_local(const int* __restrict__ counts,
                                                   int* __restrict__ row_ptr,
                                                   int* __restrict__ blockSums,
                                                   int N) {
    __shared__ int s[1024];
    int tid = threadIdx.x;
    int g = blockIdx.x * 1024 + tid;
    int v = (g < N) ? counts[g] : 0;
    s[tid] = v;
    __syncthreads();
    for (int off = 1; off < 1024; off <<= 1) {
        int t = (tid >= off) ? s[tid - off] : 0;
        __syncthreads();
        s[tid] += t;
        __syncthreads();
    }
    if (g < N) row_ptr[g] = s[tid] - v;  // exclusive
    if (tid == 1023) blockSums[blockIdx.x] = s[1023];
}

// ---- CSR build step 2b: serial exclusive scan of block sums (tiny, B~147) ----
__global__ void scan_sums(int* __restrict__ blockSums, int B) {
    if (threadIdx.x != 0 || blockIdx.x != 0) return;
    int run = 0;
    for (int i = 0; i < B; ++i) {
        int v = blockSums[i];
        blockSums[i] = run;
        run += v;
    }
}

// ---- CSR build step 2c: add block offsets ----
__global__ __launch_bounds__(1024) void scan_add(int* __restrict__ row_ptr,
                                                 const int* __restrict__ blockSums,
                                                 int N) {
    int g = blockIdx.x * 1024 + threadIdx.x;
    if (g < N) row_ptr[g] += blockSums[blockIdx.x];
}

// ---- CSR build step 3: scatter edges into row-sorted order ----
__global__ __launch_bounds__(256) void edge_scatter(const int2* __restrict__ idx2,
                                                    const float* __restrict__ adj,
                                                    const int* __restrict__ row_ptr,
                                                    int* __restrict__ cursor,
                                                    int2* __restrict__ colw,
                                                    long long nnz) {
    long long e = (long long)blockIdx.x * blockDim.x + threadIdx.x;
    if (e >= nnz) return;
    int2 rc = idx2[e];
    int pos = row_ptr[rc.x] + atomicAdd(&cursor[rc.x], 1);
    colw[pos] = make_int2(rc.y, __float_as_int(adj[e]));
}

// ---- SpMM gather: one 64-lane wave per row, 4 edges x 16 float4-lanes/iter ----
__global__ __launch_bounds__(256) void spmm_csr(const int2* __restrict__ colw,
                                                const int* __restrict__ row_ptr,
                                                const int* __restrict__ counts,
                                                const float* __restrict__ e_cur,
                                                float* __restrict__ e_next,
                                                int N) {
    int row = blockIdx.x * 4 + (threadIdx.x >> 6);
    if (row >= N) return;
    int lane = threadIdx.x & 63;
    int eg = lane >> 4;    // edge group 0..3
    int sub = lane & 15;   // float4 slot 0..15
    int start = row_ptr[row];
    int len = counts[row];
    float4 acc = make_float4(0.f, 0.f, 0.f, 0.f);
    #pragma unroll 2
    for (int e = eg; e < len; e += 4) {
        int2 cw = colw[start + e];
        float w = __int_as_float(cw.y);
        const float4* src = (const float4*)(e_cur + (size_t)cw.x * D);
        float4 v = src[sub];
        acc.x += w * v.x;
        acc.y += w * v.y;
        acc.z += w * v.z;
        acc.w += w * v.w;
    }
    // reduce across the 4 edge groups (lane xor 16, 32)
    acc.x += __shfl_xor(acc.x, 16, 64); acc.y += __shfl_xor(acc.y, 16, 64);
    acc.z += __shfl_xor(acc.z, 16, 64); acc.w += __shfl_xor(acc.w, 16, 64);
    acc.x += __shfl_xor(acc.x, 32, 64); acc.y += __shfl_xor(acc.y, 32, 64);
    acc.z += __shfl_xor(acc.z, 32, 64); acc.w += __shfl_xor(acc.w, 32, 64);
    if (lane < 16) {
        float4* dst = (float4*)(e_next + (size_t)row * D);
        dst[sub] = acc;
    }
}

// ---- fold one layer's gathered rows into the query accumulators ----
__global__ __launch_bounds__(64) void gather_acc(const float* __restrict__ e,
                                                 const int* __restrict__ uidx,
                                                 const int* __restrict__ iidx,
                                                 float* __restrict__ accU,
                                                 float* __restrict__ accI,
                                                 int n_users) {
    int j = blockIdx.x;
    int lane = threadIdx.x;
    accU[(size_t)j * D + lane] += e[(size_t)uidx[j] * D + lane];
    accI[(size_t)j * D + lane] += e[((size_t)n_users + iidx[j]) * D + lane];
}

// ---- final dot: out[j] = dot(accU[j]/4, accI[j]/4) ----
__global__ __launch_bounds__(64) void final_dot(const float* __restrict__ accU,
                                                const float* __restrict__ accI,
                                                float* __restrict__ out) {
    int j = blockIdx.x;
    int lane = threadIdx.x;
    float p = accU[(size_t)j * D + lane] * accI[(size_t)j * D + lane];
    #pragma unroll
    for (int off = 32; off > 0; off >>= 1) p += __shfl_down(p, off);
    if (lane == 0) out[j] = p * (1.0f / 16.0f);
}

extern "C" void kernel_launch(void* const* d_in, const int* in_sizes, int n_in,
                              void* d_out, int out_size, void* d_ws, size_t ws_size,
                              hipStream_t stream) {
    const float* user_emb = (const float*)d_in[0];
    const float* item_emb = (const float*)d_in[1];
    const float* adj_data = (const float*)d_in[2];
    const int* adj_indices = (const int*)d_in[3];
    const int* user_idx = (const int*)d_in[4];
    const int* item_idx = (const int*)d_in[5];
    float* out = (float*)d_out;

    const int n_users = in_sizes[0] / D;
    const int n_items = in_sizes[1] / D;
    const long long nnz = in_sizes[2];
    const int N = n_users + n_items;
    const int nq = in_sizes[4];

    // ---- workspace layout (16B aligned slices) ----
    char* p = (char*)d_ws;
    float* e0 = (float*)p;              p += (size_t)N * D * sizeof(float);
    float* e1 = (float*)p;              p += (size_t)N * D * sizeof(float);
    float* accU = (float*)p;            p += (size_t)nq * D * sizeof(float);
    float* accI = (float*)p;            p += (size_t)nq * D * sizeof(float);
    int2* colw = (int2*)p;              p += (size_t)nnz * sizeof(int2);
    int* counts = (int*)p;              p += ((size_t)N * 4 + 255) / 256 * 256;
    int* row_ptr = (int*)p;             p += ((size_t)N * 4 + 255) / 256 * 256;
    int* cursor = (int*)p;              p += ((size_t)N * 4 + 255) / 256 * 256;
    int* blockSums = (int*)p;           p += 4096;

    const int2* idx2 = (const int2*)adj_indices;
    const int scanB = (N + 1023) / 1024;

    // ---- e0 = concat(user_emb, item_emb) ----
    {
        long long total4 = (long long)N * (D / 4);
        long long nU4 = (long long)n_users * (D / 4);
        concat_copy<<<(int)((total4 + 255) / 256), 256, 0, stream>>>(
            (const float4*)user_emb, (const float4*)item_emb, (float4*)e0, nU4, total4);
    }
    gather_init<<<nq, 64, 0, stream>>>(user_emb, item_emb, user_idx, item_idx, accU, accI);

    // ---- CSR build (once; edges identical across layers) ----
    hipMemsetAsync(counts, 0, (size_t)N * sizeof(int), stream);
    hipMemsetAsync(cursor, 0, (size_t)N * sizeof(int), stream);
    {
        int blocks = (int)((nnz + 255) / 256);
        edge_hist<<<blocks, 256, 0, stream>>>(idx2, counts, nnz);
        scan_local<<<scanB, 1024, 0, stream>>>(counts, row_ptr, blockSums, N);
        scan_sums<<<1, 64, 0, stream>>>(blockSums, scanB);
        scan_add<<<scanB, 1024, 0, stream>>>(row_ptr, blockSums, N);
        edge_scatter<<<blocks, 256, 0, stream>>>(idx2, adj_data, row_ptr, cursor, colw, nnz);
    }

    // ---- 3 layers of SpMM + query-row accumulation ----
    const int spmm_blocks = (N + 3) / 4;
    float* cur = e0;
    float* nxt = e1;
    for (int layer = 0; layer < 3; ++layer) {
        spmm_csr<<<spmm_blocks, 256, 0, stream>>>(colw, row_ptr, counts, cur, nxt, N);
        gather_acc<<<nq, 64, 0, stream>>>(nxt, user_idx, item_idx, accU, accI, n_users);
        float* tmp = cur; cur = nxt; nxt = tmp;
    }

    final_dot<<<nq, 64, 0, stream>>>(accU, accI, out);
}